// Round 1
// 680.888 us; speedup vs baseline: 1.0217x; 1.0217x over previous
//
#include <hip/hip_runtime.h>

// ---------------------------------------------------------------------------
// MHAMixer: 2 linear heads + 2 conv1d(k=3) heads -> attention -> concat -> proj
// All GEMMs: bf16 MFMA 16x16x32, 128x128 tile, BK=32, global_load_lds staging
// (m97 structure). B-operands pre-transposed to [N][K] for contiguous frags.
// This version: softmax kernel eliminated. sgemm emits per-tile row (max,sum)
// partials; av does flash-combine + exp-normalize inline (writes normalized
// f32 att output + feeds bf16 P straight into the PV MFMA loop).
// ---------------------------------------------------------------------------

using bf16_t = __bf16;
using bf16x8 = __attribute__((ext_vector_type(8))) __bf16;
using bf16x4 = __attribute__((ext_vector_type(4))) __bf16;
using f32x4  = __attribute__((ext_vector_type(4))) float;

#define NB   16
#define SL   1024
#define DIN  512
#define DQK  128
#define NH   4

#define BK 32

constexpr size_t XPAD_ROWS  = (size_t)NB * (SL + 2);          // 16*1026
constexpr size_t XPAD_PER   = XPAD_ROWS * DIN;                // 8,404,992
constexpr size_t XPAD_ELEMS = 3 * XPAD_PER;
constexpr size_t WT_ELEMS   = (size_t)3 * NH * 3 * DQK * DIN; // 2,359,296
constexpr size_t PWT_ELEMS  = (size_t)DIN * DIN;              // 262,144
constexpr size_t BIAS_ELEMS = (size_t)3 * NH * DQK;           // 1536
constexpr size_t QH_ELEMS   = (size_t)NH * NB * SL * DQK;     // 8,388,608
constexpr size_t PART_ELEMS = (size_t)NH * NB * 8 * SL;       // 524,288 float2
constexpr size_t CAT_ELEMS  = (size_t)NB * SL * (NH * DQK);   // 8,388,608

#define INV_SQRT_DK 0.08838834764831845f

__device__ __forceinline__ void load_lds_16B(const void* g, void* l) {
  __builtin_amdgcn_global_load_lds((const __attribute__((address_space(1))) void*)g,
                                   (__attribute__((address_space(3))) void*)l, 16, 0, 0);
}

// 128x128 output tile, 4 waves (2x2), each wave 4x4 of 16x16x32 MFMA.
// A: [M][K] row-major (lda elems), Bt: [N][K] row-major (ldb elems). K % 32 == 0.
__device__ __forceinline__ void gemm_core(const bf16_t* __restrict__ Ab, int lda,
                                          const bf16_t* __restrict__ Bb, int ldb,
                                          int K, f32x4 acc[4][4],
                                          bf16_t* lgA, bf16_t* lgB) {
  const int tid  = threadIdx.x;
  const int wave = tid >> 6;
  const int lane = tid & 63;
  const int quad = lane >> 4;
  const int l16  = lane & 15;
  const int wr   = wave >> 1;
  const int wc   = wave & 1;
  const int lrow = lane >> 2;        // 0..15: row within 16-row chunk
  const int lcol = (lane & 3) << 3;  // 0,8,16,24: element offset within row

  for (int k0 = 0; k0 < K; k0 += BK) {
    __syncthreads();   // previous iter's LDS reads done before overwrite
#pragma unroll
    for (int c = 0; c < 2; ++c) {
      const int chunk = wave * 2 + c;           // 8 chunks of 16 rows
      const int r = chunk * 16 + lrow;
      load_lds_16B(Ab + (size_t)r * lda + k0 + lcol, lgA + chunk * 512);
      load_lds_16B(Bb + (size_t)r * ldb + k0 + lcol, lgB + chunk * 512);
    }
    __syncthreads();   // drains vmcnt (compiler) -> LDS tiles visible
    bf16x8 af[4], bfr[4];
#pragma unroll
    for (int i = 0; i < 4; ++i)
      af[i] = *(const bf16x8*)(lgA + (wr * 64 + i * 16 + l16) * BK + quad * 8);
#pragma unroll
    for (int i = 0; i < 4; ++i)
      bfr[i] = *(const bf16x8*)(lgB + (wc * 64 + i * 16 + l16) * BK + quad * 8);
#pragma unroll
    for (int mi = 0; mi < 4; ++mi)
#pragma unroll
      for (int ni = 0; ni < 4; ++ni)
        acc[mi][ni] = __builtin_amdgcn_mfma_f32_16x16x32_bf16(af[mi], bfr[ni],
                                                              acc[mi][ni], 0, 0, 0);
  }
}

#define GEMM_PROLOGUE()                                    \
  __shared__ __align__(16) bf16_t lgA[128 * BK];           \
  __shared__ __align__(16) bf16_t lgB[128 * BK];           \
  f32x4 acc[4][4];                                         \
  {                                                        \
    f32x4 z = {0.f, 0.f, 0.f, 0.f};                        \
    _Pragma("unroll") for (int i = 0; i < 4; ++i)          \
      _Pragma("unroll") for (int j = 0; j < 4; ++j)        \
        acc[i][j] = z;                                     \
  }

#define EPILOGUE_VARS()                                    \
  const int wave = threadIdx.x >> 6;                       \
  const int lane = threadIdx.x & 63;                       \
  const int quad = lane >> 4;                              \
  const int l16  = lane & 15;                              \
  const int wr   = wave >> 1;                              \
  const int wc   = wave & 1;

// --------------------------- prep kernels ----------------------------------

// pad+cast q/k/v -> bf16 [3][NB][1026][DIN], rows 0 and 1025 zeroed per batch
__global__ void cast_pad_kernel(const float* __restrict__ q,
                                const float* __restrict__ k,
                                const float* __restrict__ v,
                                bf16_t* __restrict__ xpad) {
  size_t i = (size_t)blockIdx.x * blockDim.x + threadIdx.x;  // 8-elem group
  if (i >= XPAD_ELEMS / 8) return;
  int    s    = (int)(i / (XPAD_PER / 8));
  size_t r    = i % (XPAD_PER / 8);
  size_t rowg = r >> 6;                 // b*1026 + padded row
  int    c0   = (int)(r & 63) * 8;
  size_t b    = rowg / (SL + 2);
  int    row  = (int)(rowg % (SL + 2));
  const float* src = (s == 0) ? q : ((s == 1) ? k : v);
  bf16x8 o;
  if (row == 0 || row == SL + 1) {
#pragma unroll
    for (int j = 0; j < 8; ++j) o[j] = (bf16_t)0.f;
  } else {
    const float* p = src + ((b * SL) + row - 1) * DIN + c0;
    const float4 f0 = ((const float4*)p)[0];
    const float4 f1 = ((const float4*)p)[1];
    o[0] = (bf16_t)f0.x; o[1] = (bf16_t)f0.y; o[2] = (bf16_t)f0.z; o[3] = (bf16_t)f0.w;
    o[4] = (bf16_t)f1.x; o[5] = (bf16_t)f1.y; o[6] = (bf16_t)f1.z; o[7] = (bf16_t)f1.w;
  }
  *(bf16x8*)(xpad + i * 8) = o;
}

// Wt  [3][4][3][DQK][DIN] bf16 (B^T per src/head/tap; learnable: tap1 only)
// pwt [DIN][DIN] bf16 = proj_w^T ; bias [3][4][DQK] f32
__global__ void prep_w_kernel(const float* __restrict__ lw_q, const float* __restrict__ lw_k,
                              const float* __restrict__ lw_v, const float* __restrict__ lb_q,
                              const float* __restrict__ lb_k, const float* __restrict__ lb_v,
                              const float* __restrict__ cw_q, const float* __restrict__ cw_k,
                              const float* __restrict__ cw_v, const float* __restrict__ cb_q,
                              const float* __restrict__ cb_k, const float* __restrict__ cb_v,
                              const float* __restrict__ proj_w,
                              bf16_t* __restrict__ Wt, float* __restrict__ bias,
                              bf16_t* __restrict__ pwt) {
  size_t i = (size_t)blockIdx.x * blockDim.x + threadIdx.x;
  if (i < WT_ELEMS) {
    int kk = (int)(i % DIN);
    int n  = (int)((i / DIN) % DQK);
    int t  = (int)((i / ((size_t)DIN * DQK)) % 3);
    int h  = (int)((i / ((size_t)DIN * DQK * 3)) % NH);
    int s  = (int)(i / ((size_t)DIN * DQK * 3 * NH));
    const float* lw = (s == 0) ? lw_q : ((s == 1) ? lw_k : lw_v);
    const float* cw = (s == 0) ? cw_q : ((s == 1) ? cw_k : cw_v);
    float val;
    if (h < 2) val = (t == 1) ? lw[((size_t)h * DIN + kk) * DQK + n] : 0.f;
    else       val = cw[(((size_t)(h - 2) * DQK + n) * DIN + kk) * 3 + t];
    Wt[i] = (bf16_t)val;
  } else if (i < WT_ELEMS + PWT_ELEMS) {
    size_t j = i - WT_ELEMS;
    int n = (int)(j / DIN), kk = (int)(j % DIN);
    pwt[j] = (bf16_t)proj_w[(size_t)kk * DIN + n];
  } else if (i < WT_ELEMS + PWT_ELEMS + BIAS_ELEMS) {
    size_t j = i - WT_ELEMS - PWT_ELEMS;
    int s = (int)(j / (NH * DQK));
    int h = (int)((j / DQK) % NH);
    int n = (int)(j % DQK);
    const float* lb = (s == 0) ? lb_q : ((s == 1) ? lb_k : lb_v);
    const float* cb = (s == 0) ? cb_q : ((s == 1) ? cb_k : cb_v);
    bias[j] = (h < 2) ? lb[h * DQK + n] : cb[(h - 2) * DQK + n];
  }
}

// --------------------------- projection GEMM -------------------------------
// z = s*4 + h'. Conv heads: sum of 3 shifted GEMMs over the padded input.
// Q/K -> [h][b][l][dqk] bf16 ; V -> [h][b][dqk][l] bf16 (transposed for att*V)
// h' remap (z&3)^2 dispatches the 3x-longer conv blocks first (tail shrink).
__global__ __launch_bounds__(256, 2) void proj_kernel(
    const bf16_t* __restrict__ xpad, const bf16_t* __restrict__ Wt,
    const float* __restrict__ bias,
    bf16_t* __restrict__ Qh, bf16_t* __restrict__ Kh, bf16_t* __restrict__ Vt) {
  GEMM_PROLOGUE();
  const int mt = blockIdx.x;         // 0..127 (M=16384)
  const int z  = blockIdx.z;         // 0..11
  const int s  = z >> 2, h = (z & 3) ^ 2;   // conv heads (h=2,3) dispatch first
  const int b  = mt >> 3;
  const int l0 = (mt & 7) << 7;

  const bf16_t* Xs = xpad + (size_t)s * XPAD_PER;
  const int t0 = (h < 2) ? 1 : 0;
  const int t1 = (h < 2) ? 1 : 2;
  for (int t = t0; t <= t1; ++t) {
    const bf16_t* Ab = Xs + ((size_t)b * (SL + 2) + l0 + t) * DIN;
    const bf16_t* Bb = Wt + (((size_t)(s * NH + h) * 3 + t) * DQK) * DIN;
    gemm_core(Ab, DIN, Bb, DIN, DIN, acc, lgA, lgB);
  }

  EPILOGUE_VARS();
  const float* bs = bias + (s * NH + h) * DQK;
  if (s < 2) {
    bf16_t* outp = ((s == 0) ? Qh : Kh) + ((size_t)h * NB + b) * SL * DQK
                 + (size_t)l0 * DQK;
#pragma unroll
    for (int mi = 0; mi < 4; ++mi)
#pragma unroll
      for (int ni = 0; ni < 4; ++ni)
#pragma unroll
        for (int r = 0; r < 4; ++r) {
          int row = wr * 64 + mi * 16 + quad * 4 + r;
          int col = wc * 64 + ni * 16 + l16;
          outp[(size_t)row * DQK + col] = (bf16_t)(acc[mi][ni][r] + bs[col]);
        }
  } else {
    bf16_t* outv = Vt + ((size_t)h * NB + b) * DQK * SL;
#pragma unroll
    for (int mi = 0; mi < 4; ++mi)
#pragma unroll
      for (int ni = 0; ni < 4; ++ni)
#pragma unroll
        for (int r = 0; r < 4; ++r) {
          int row = wr * 64 + mi * 16 + quad * 4 + r;
          int col = wc * 64 + ni * 16 + l16;
          outv[(size_t)col * SL + l0 + row] = (bf16_t)(acc[mi][ni][r] + bs[col]);
        }
  }
}

// --------------------------- S = Q K^T * inv + row partials ----------------
// Writes scaled raw S (f32) and per-(row, 128-col tile) softmax partials
// (m_tile, sum exp(v - m_tile)) as float2 for flash-combine in av_kernel.
__global__ __launch_bounds__(256, 2) void sgemm_kernel(
    const bf16_t* __restrict__ Qh, const bf16_t* __restrict__ Kh,
    float* __restrict__ att, float2* __restrict__ partials) {
  GEMM_PROLOGUE();
  const int mt = blockIdx.x;   // 0..7
  const int nt = blockIdx.y;   // 0..7
  const int hb = blockIdx.z;   // 0..63
  const bf16_t* Ab = Qh + (size_t)hb * SL * DQK + (size_t)mt * 128 * DQK;
  const bf16_t* Bb = Kh + (size_t)hb * SL * DQK + (size_t)nt * 128 * DQK;
  gemm_core(Ab, DQK, Bb, DQK, DQK, acc, lgA, lgB);

  EPILOGUE_VARS();
  const int tid = threadIdx.x;
  // scale in place (raw scaled S is both the stored value and the exp input)
#pragma unroll
  for (int mi = 0; mi < 4; ++mi)
#pragma unroll
    for (int ni = 0; ni < 4; ++ni)
#pragma unroll
      for (int r = 0; r < 4; ++r)
        acc[mi][ni][r] *= INV_SQRT_DK;

  float* outp = att + (size_t)hb * SL * SL;
#pragma unroll
  for (int mi = 0; mi < 4; ++mi)
#pragma unroll
    for (int ni = 0; ni < 4; ++ni)
#pragma unroll
      for (int r = 0; r < 4; ++r) {
        int row = mt * 128 + wr * 64 + mi * 16 + quad * 4 + r;
        int col = nt * 128 + wc * 64 + ni * 16 + l16;
        outp[(size_t)row * SL + col] = acc[mi][ni][r];
      }

  // ---- per-row tile stats: max + sum(exp(v - max)) over this block's 128 cols
  __syncthreads();                      // all lgA/lgB frag reads complete
  float* smM = (float*)lgA;             // [128][2] (wc halves)
  float* smS = smM + 256;
#pragma unroll
  for (int mi = 0; mi < 4; ++mi)
#pragma unroll
    for (int r = 0; r < 4; ++r) {
      float m = acc[mi][0][r];
#pragma unroll
      for (int ni = 1; ni < 4; ++ni) m = fmaxf(m, acc[mi][ni][r]);
      m = fmaxf(m, __shfl_xor(m, 1, 64));
      m = fmaxf(m, __shfl_xor(m, 2, 64));
      m = fmaxf(m, __shfl_xor(m, 4, 64));
      m = fmaxf(m, __shfl_xor(m, 8, 64));
      float s = 0.f;
#pragma unroll
      for (int ni = 0; ni < 4; ++ni) s += __expf(acc[mi][ni][r] - m);
      s += __shfl_xor(s, 1, 64);
      s += __shfl_xor(s, 2, 64);
      s += __shfl_xor(s, 4, 64);
      s += __shfl_xor(s, 8, 64);
      if (l16 == 0) {
        int row = wr * 64 + mi * 16 + quad * 4 + r;
        smM[row * 2 + wc] = m;
        smS[row * 2 + wc] = s;
      }
    }
  __syncthreads();
  if (tid < 128) {
    float m0 = smM[tid * 2], m1 = smM[tid * 2 + 1];
    float s0 = smS[tid * 2], s1 = smS[tid * 2 + 1];
    float m = fmaxf(m0, m1);
    float s = s0 * __expf(m0 - m) + s1 * __expf(m1 - m);
    partials[((size_t)hb * 8 + nt) * SL + (size_t)mt * 128 + tid] =
        make_float2(m, s);
  }
}

// ---------------- fused softmax + out = scale * softmax(S) @ V -------------
// Flash-combine of the 8 tile partials gives per-row (max, 1/sum). The K-loop
// reg-stages A: read raw S f32, p = exp(v-m)*inv, write normalized f32 back
// (the required att output), cast to bf16 -> LDS A tile, MFMA against V.
// A f32 loads are prefetched one K-step ahead (latency hides under MFMA; the
// pre-barrier vmcnt drain realizes the overlap).
__global__ __launch_bounds__(256, 2) void av_kernel(
    float* __restrict__ att, const float2* __restrict__ partials,
    const bf16_t* __restrict__ Vt,
    const float* __restrict__ lscale, const float* __restrict__ cscale,
    bf16_t* __restrict__ cat) {
  __shared__ __align__(16) bf16_t lgA[128 * BK];
  __shared__ __align__(16) bf16_t lgB[128 * BK];
  __shared__ float rowM[128];
  __shared__ float rowInv[128];
  f32x4 acc[4][4];
  {
    f32x4 z = {0.f, 0.f, 0.f, 0.f};
#pragma unroll
    for (int i = 0; i < 4; ++i)
#pragma unroll
      for (int j = 0; j < 4; ++j) acc[i][j] = z;
  }
  const int mt = blockIdx.x;   // 0..7
  const int hb = blockIdx.z;   // 0..63
  const int h = hb >> 4, b = hb & 15;
  const int tid = threadIdx.x;

  // phase 0: flash-combine tile partials -> per-row max and 1/sum
  if (tid < 128) {
    const size_t g = (size_t)mt * 128 + tid;
    float2 t[8];
    float m = -__builtin_inff();
#pragma unroll
    for (int nt = 0; nt < 8; ++nt) {
      t[nt] = partials[((size_t)hb * 8 + nt) * SL + g];
      m = fmaxf(m, t[nt].x);
    }
    float s = 0.f;
#pragma unroll
    for (int nt = 0; nt < 8; ++nt) s += t[nt].y * __expf(t[nt].x - m);
    rowM[tid] = m;
    rowInv[tid] = 1.0f / s;
  }
  __syncthreads();

  const int arow = tid >> 1;           // A staging: 2 threads per row
  const int acol = (tid & 1) * 16;     // each thread: 16 f32 of the 32-wide tile
  const float rm = rowM[arow];
  const float ri = rowInv[arow];
  float* Sp = att + (size_t)hb * SL * SL + ((size_t)mt * 128 + arow) * SL + acol;

  const int wave = tid >> 6;
  const int lane = tid & 63;
  const int quad = lane >> 4;
  const int l16  = lane & 15;
  const int wr   = wave >> 1;
  const int wc   = wave & 1;
  const int lrow = lane >> 2;
  const int lcol = (lane & 3) << 3;
  const bf16_t* Bb = Vt + (size_t)hb * DQK * SL;

  // prefetch first A tile
  float4 f0 = ((const float4*)Sp)[0];
  float4 f1 = ((const float4*)Sp)[1];
  float4 f2 = ((const float4*)Sp)[2];
  float4 f3 = ((const float4*)Sp)[3];

  for (int k0 = 0; k0 < SL; k0 += BK) {
    __syncthreads();   // previous iter's LDS frag reads done
    // transform current A tile: p = exp(v - m) * inv
    float4 p0, p1, p2, p3;
    p0.x = __expf(f0.x - rm) * ri; p0.y = __expf(f0.y - rm) * ri;
    p0.z = __expf(f0.z - rm) * ri; p0.w = __expf(f0.w - rm) * ri;
    p1.x = __expf(f1.x - rm) * ri; p1.y = __expf(f1.y - rm) * ri;
    p1.z = __expf(f1.z - rm) * ri; p1.w = __expf(f1.w - rm) * ri;
    p2.x = __expf(f2.x - rm) * ri; p2.y = __expf(f2.y - rm) * ri;
    p2.z = __expf(f2.z - rm) * ri; p2.w = __expf(f2.w - rm) * ri;
    p3.x = __expf(f3.x - rm) * ri; p3.y = __expf(f3.y - rm) * ri;
    p3.z = __expf(f3.z - rm) * ri; p3.w = __expf(f3.w - rm) * ri;
    // normalized f32 att output (in-place over raw S)
    ((float4*)(Sp + k0))[0] = p0;
    ((float4*)(Sp + k0))[1] = p1;
    ((float4*)(Sp + k0))[2] = p2;
    ((float4*)(Sp + k0))[3] = p3;
    // bf16 P -> LDS A tile [128][32] linear
    bf16x8 o0 = {(bf16_t)p0.x, (bf16_t)p0.y, (bf16_t)p0.z, (bf16_t)p0.w,
                 (bf16_t)p1.x, (bf16_t)p1.y, (bf16_t)p1.z, (bf16_t)p1.w};
    bf16x8 o1 = {(bf16_t)p2.x, (bf16_t)p2.y, (bf16_t)p2.z, (bf16_t)p2.w,
                 (bf16_t)p3.x, (bf16_t)p3.y, (bf16_t)p3.z, (bf16_t)p3.w};
    *(bf16x8*)(lgA + arow * BK + acol)     = o0;
    *(bf16x8*)(lgA + arow * BK + acol + 8) = o1;
    // prefetch next A tile (covered by the pre-barrier vmcnt drain)
    if (k0 + BK < SL) {
      f0 = ((const float4*)(Sp + k0 + BK))[0];
      f1 = ((const float4*)(Sp + k0 + BK))[1];
      f2 = ((const float4*)(Sp + k0 + BK))[2];
      f3 = ((const float4*)(Sp + k0 + BK))[3];
    }
    // B stage: V tile via global_load_lds
#pragma unroll
    for (int c = 0; c < 2; ++c) {
      const int chunk = wave * 2 + c;
      const int r = chunk * 16 + lrow;
      load_lds_16B(Bb + (size_t)r * SL + k0 + lcol, lgB + chunk * 512);
    }
    __syncthreads();   // drains lgkmcnt + vmcnt -> tiles visible
    bf16x8 af[4], bfr[4];
#pragma unroll
    for (int i = 0; i < 4; ++i)
      af[i] = *(const bf16x8*)(lgA + (wr * 64 + i * 16 + l16) * BK + quad * 8);
#pragma unroll
    for (int i = 0; i < 4; ++i)
      bfr[i] = *(const bf16x8*)(lgB + (wc * 64 + i * 16 + l16) * BK + quad * 8);
#pragma unroll
    for (int mi = 0; mi < 4; ++mi)
#pragma unroll
      for (int ni = 0; ni < 4; ++ni)
        acc[mi][ni] = __builtin_amdgcn_mfma_f32_16x16x32_bf16(af[mi], bfr[ni],
                                                              acc[mi][ni], 0, 0, 0);
  }

  const float sc = (h < 2) ? lscale[h] : cscale[h - 2];
  bf16_t* outp = cat + (size_t)b * SL * (NH * DQK) + (size_t)(mt * 128) * (NH * DQK)
               + h * DQK;
#pragma unroll
  for (int mi = 0; mi < 4; ++mi)
#pragma unroll
    for (int ni = 0; ni < 4; ++ni)
#pragma unroll
      for (int r = 0; r < 4; ++r) {
        int row = wr * 64 + mi * 16 + quad * 4 + r;
        int col = wc * 64 + ni * 16 + l16;
        outp[(size_t)row * (NH * DQK) + col] = (bf16_t)(acc[mi][ni][r] * sc);
      }
}

// --------------------------- final projection ------------------------------
__global__ __launch_bounds__(256, 2) void final_kernel(
    const bf16_t* __restrict__ cat, const bf16_t* __restrict__ pwt,
    const float* __restrict__ pb, float* __restrict__ outp) {
  GEMM_PROLOGUE();
  const int mt = blockIdx.x;   // 0..127
  const int nt = blockIdx.y;   // 0..3
  const bf16_t* Ab = cat + (size_t)mt * 128 * DIN;
  const bf16_t* Bb = pwt + (size_t)nt * 128 * DIN;
  gemm_core(Ab, DIN, Bb, DIN, DIN, acc, lgA, lgB);

  EPILOGUE_VARS();
#pragma unroll
  for (int mi = 0; mi < 4; ++mi)
#pragma unroll
    for (int ni = 0; ni < 4; ++ni)
#pragma unroll
      for (int r = 0; r < 4; ++r) {
        int row = mt * 128 + wr * 64 + mi * 16 + quad * 4 + r;
        int col = nt * 128 + wc * 64 + ni * 16 + l16;
        outp[(size_t)row * DIN + col] = acc[mi][ni][r] + pb[nt * 128 + col];
      }
}

// ---------------------------------------------------------------------------

extern "C" void kernel_launch(void* const* d_in, const int* in_sizes, int n_in,
                              void* d_out, int out_size, void* d_ws, size_t ws_size,
                              hipStream_t stream) {
  const float* q      = (const float*)d_in[0];
  const float* k      = (const float*)d_in[1];
  const float* v      = (const float*)d_in[2];
  const float* lw_q   = (const float*)d_in[3];
  const float* lb_q   = (const float*)d_in[4];
  const float* lw_k   = (const float*)d_in[5];
  const float* lb_k   = (const float*)d_in[6];
  const float* lw_v   = (const float*)d_in[7];
  const float* lb_v   = (const float*)d_in[8];
  const float* lscale = (const float*)d_in[9];
  const float* cw_q   = (const float*)d_in[10];
  const float* cb_q   = (const float*)d_in[11];
  const float* cw_k   = (const float*)d_in[12];
  const float* cb_k   = (const float*)d_in[13];
  const float* cw_v   = (const float*)d_in[14];
  const float* cb_v   = (const float*)d_in[15];
  const float* cscale = (const float*)d_in[16];
  const float* proj_w = (const float*)d_in[17];
  const float* proj_b = (const float*)d_in[18];

  char* ws = (char*)d_ws;
  size_t off = 0;
  bf16_t* xpad  = (bf16_t*)(ws + off); off += XPAD_ELEMS * 2;   // 50.4 MB
  bf16_t* Wt    = (bf16_t*)(ws + off); off += WT_ELEMS * 2;     //  4.7 MB
  float*  bias  = (float*) (ws + off); off += BIAS_ELEMS * 4;
  bf16_t* pwt   = (bf16_t*)(ws + off); off += PWT_ELEMS * 2;
  bf16_t* Qh    = (bf16_t*)(ws + off); off += QH_ELEMS * 2;     // 16.8 MB
  bf16_t* Kh    = (bf16_t*)(ws + off); off += QH_ELEMS * 2;     // 16.8 MB
  bf16_t* Vt    = (bf16_t*)(ws + off); off += QH_ELEMS * 2;     // 16.8 MB
  float2* parts = (float2*)(ws + off); off += PART_ELEMS * 8;   //  4.2 MB
  bf16_t* cat   = (bf16_t*)(ws + off); off += CAT_ELEMS * 2;    // 16.8 MB
  // total ~127 MB of d_ws

  float* outp = (float*)d_out;
  float* att  = outp + (size_t)NB * SL * DIN;   // 4x[16,1024,1024] f32 region

  {
    int nblk = (int)((XPAD_ELEMS / 8 + 255) / 256);
    cast_pad_kernel<<<nblk, 256, 0, stream>>>(q, k, v, xpad);
  }
  {
    size_t tot = WT_ELEMS + PWT_ELEMS + BIAS_ELEMS;
    int nblk = (int)((tot + 255) / 256);
    prep_w_kernel<<<nblk, 256, 0, stream>>>(lw_q, lw_k, lw_v, lb_q, lb_k, lb_v,
                                            cw_q, cw_k, cw_v, cb_q, cb_k, cb_v,
                                            proj_w, Wt, bias, pwt);
  }
  proj_kernel<<<dim3(128, 1, 12), 256, 0, stream>>>(xpad, Wt, bias, Qh, Kh, Vt);
  sgemm_kernel<<<dim3(8, 8, 64), 256, 0, stream>>>(Qh, Kh, att, parts);
  av_kernel<<<dim3(8, 1, 64), 256, 0, stream>>>(att, parts, Vt, lscale, cscale, cat);
  final_kernel<<<dim3(128, 4, 1), 256, 0, stream>>>(cat, pwt, proj_b, outp);
}